// Round 1
// baseline (902.581 us; speedup 1.0000x reference)
//
#include <hip/hip_runtime.h>

#define H_ 128
#define W_ 128
#define B_ 8
#define C_ 64
#define HW_ (H_*W_)
#define K_ 9

#define TX 32
#define TY 8
#define CSTEP 16

// ---- weight transpose: wt[(cin*9+k)*64 + co] = w[((co*64)+cin)*9 + k] ----
__global__ void wtrans_kernel(const float* __restrict__ w, float* __restrict__ wt) {
    int t = blockIdx.x * 256 + threadIdx.x;   // enumerates [co][cin][k]
    if (t >= C_ * C_ * K_) return;
    int kk  = t % K_;
    int cin = (t / K_) % C_;
    int co  = t / (K_ * C_);
    wt[(cin * K_ + kk) * C_ + co] = w[t];
}

// ---- 1x1 offset conv: of[B,2,H,W] -> off[B,18,H,W] ----
__global__ void offconv_kernel(const float* __restrict__ of,
                               const float* __restrict__ w,   // [18][2]
                               const float* __restrict__ b,   // [18]
                               float* __restrict__ out) {
    int t = blockIdx.x * 256 + threadIdx.x;  // over B*HW
    if (t >= B_ * HW_) return;
    int bi = t >> 14;            // / HW_
    int p  = t & (HW_ - 1);
    float a0 = of[(bi * 2 + 0) * HW_ + p];
    float a1 = of[(bi * 2 + 1) * HW_ + p];
#pragma unroll
    for (int c = 0; c < 18; ++c) {
        out[(bi * 18 + c) * HW_ + p] = b[c] + w[c * 2] * a0 + w[c * 2 + 1] * a1;
    }
}

// ---- 3x3 conv + bias + relu, pad 1. wt layout [cin][9][cout] ----
__global__ __launch_bounds__(256, 2)
void conv3x3_relu_kernel(const float* __restrict__ in,    // [B][C][H][W]
                         const float* __restrict__ wt,    // [C][9][C]
                         const float* __restrict__ bias,  // [C]
                         float* __restrict__ out) {       // [B][C][H][W]
    __shared__ float tile[CSTEP][TY + 2][TX + 2];  // 16 x 10 x 34 = 21.3 KB
    const int tid = threadIdx.x;
    const int tx = tid & 31, ty = tid >> 5;
    const int x0 = blockIdx.x * TX, y0 = blockIdx.y * TY;
    const int b = blockIdx.z;
    const int x = x0 + tx, y = y0 + ty;

    float acc[C_];
#pragma unroll
    for (int c = 0; c < C_; ++c) acc[c] = 0.f;

    for (int c0 = 0; c0 < C_; c0 += CSTEP) {
        __syncthreads();
        // stage input tile (zero-padded borders)
        for (int idx = tid; idx < CSTEP * (TY + 2) * (TX + 2); idx += 256) {
            int ci  = idx / ((TY + 2) * (TX + 2));
            int rem = idx - ci * ((TY + 2) * (TX + 2));
            int r   = rem / (TX + 2);
            int cc  = rem - r * (TX + 2);
            int gy = y0 - 1 + r, gx = x0 - 1 + cc;
            float v = 0.f;
            if (gy >= 0 && gy < H_ && gx >= 0 && gx < W_)
                v = in[((b * C_ + c0 + ci) * H_ + gy) * W_ + gx];
            tile[ci][r][cc] = v;
        }
        __syncthreads();
        for (int ci = 0; ci < CSTEP; ++ci) {
            float v[9];
#pragma unroll
            for (int r = 0; r < 3; ++r)
#pragma unroll
                for (int cc = 0; cc < 3; ++cc)
                    v[r * 3 + cc] = tile[ci][ty + r][tx + cc];
            const float* wrow = &wt[(c0 + ci) * 9 * C_];
#pragma unroll
            for (int kk = 0; kk < 9; ++kk) {
#pragma unroll
                for (int co = 0; co < C_; ++co)
                    acc[co] = fmaf(v[kk], wrow[kk * C_ + co], acc[co]);
            }
        }
    }
#pragma unroll
    for (int co = 0; co < C_; ++co) {
        float r = acc[co] + bias[co];
        r = r > 0.f ? r : 0.f;
        out[((b * C_ + co) * H_ + y) * W_ + x] = r;
    }
}

// ---- deformable conv 3x3 (dg=1), zeros padding, bilinear ----
__global__ __launch_bounds__(256, 2)
void deform_kernel(const float* __restrict__ h,    // [B][C][H][W]
                   const float* __restrict__ off,  // [B][18][H][W]
                   const float* __restrict__ wt,   // [C][9][C] (cin,k,co)
                   const float* __restrict__ bias, // [C]
                   float* __restrict__ out) {      // [B][C][H][W]
    int t = blockIdx.x * 256 + threadIdx.x;  // over B*HW
    int b = t >> 14;
    int p = t & (HW_ - 1);
    int y = p >> 7;
    int x = p & (W_ - 1);

    float acc[C_];
#pragma unroll
    for (int c = 0; c < C_; ++c) acc[c] = 0.f;

    const float* offb = off + (size_t)b * 18 * HW_;
    const float* hb   = h + (size_t)b * C_ * HW_;

#pragma unroll
    for (int kk = 0; kk < 9; ++kk) {
        float oy = offb[(2 * kk + 0) * HW_ + p];
        float ox = offb[(2 * kk + 1) * HW_ + p];
        float py = (float)(y + kk / 3 - 1) + oy;
        float px = (float)(x + kk % 3 - 1) + ox;
        float y0f = floorf(py), x0f = floorf(px);
        float fy = py - y0f, fx = px - x0f;
        int iy0 = (int)y0f, ix0 = (int)x0f;
        int iy1 = iy0 + 1, ix1 = ix0 + 1;
        bool vy0 = (iy0 >= 0) && (iy0 < H_);
        bool vy1 = (iy1 >= 0) && (iy1 < H_);
        bool vx0 = (ix0 >= 0) && (ix0 < W_);
        bool vx1 = (ix1 >= 0) && (ix1 < W_);
        int cy0 = min(max(iy0, 0), H_ - 1), cy1 = min(max(iy1, 0), H_ - 1);
        int cx0 = min(max(ix0, 0), W_ - 1), cx1 = min(max(ix1, 0), W_ - 1);
        float w00 = (1.f - fy) * (1.f - fx) * ((vy0 && vx0) ? 1.f : 0.f);
        float w01 = (1.f - fy) * fx        * ((vy0 && vx1) ? 1.f : 0.f);
        float w10 = fy * (1.f - fx)        * ((vy1 && vx0) ? 1.f : 0.f);
        float w11 = fy * fx                * ((vy1 && vx1) ? 1.f : 0.f);
        int i00 = cy0 * W_ + cx0, i01 = cy0 * W_ + cx1;
        int i10 = cy1 * W_ + cx0, i11 = cy1 * W_ + cx1;
        for (int cin = 0; cin < C_; ++cin) {
            const float* hc = hb + cin * HW_;
            float v = w00 * hc[i00] + w01 * hc[i01] + w10 * hc[i10] + w11 * hc[i11];
            const float* wr = wt + (cin * 9 + kk) * C_;
#pragma unroll
            for (int co = 0; co < C_; ++co)
                acc[co] = fmaf(v, wr[co], acc[co]);
        }
    }
#pragma unroll
    for (int co = 0; co < C_; ++co)
        out[((size_t)b * C_ + co) * HW_ + p] = acc[co] + bias[co];
}

extern "C" void kernel_launch(void* const* d_in, const int* in_sizes, int n_in,
                              void* d_out, int out_size, void* d_ws, size_t ws_size,
                              hipStream_t stream) {
    const float* x     = (const float*)d_in[0];
    const float* of    = (const float*)d_in[1];
    const float* w1    = (const float*)d_in[2];
    const float* b1    = (const float*)d_in[3];
    const float* w2    = (const float*)d_in[4];
    const float* b2    = (const float*)d_in[5];
    const float* w3    = (const float*)d_in[6];
    const float* b3    = (const float*)d_in[7];
    const float* w_off = (const float*)d_in[8];
    const float* b_off = (const float*)d_in[9];
    const float* w_d   = (const float*)d_in[10];
    const float* b_d   = (const float*)d_in[11];
    float* out = (float*)d_out;

    float* ws   = (float*)d_ws;
    float* h1   = ws;                             // B*C*HW floats (33.5 MB)
    float* offb = h1 + (size_t)B_ * C_ * HW_;     // B*18*HW floats (9.4 MB)
    float* wt1  = offb + (size_t)B_ * 18 * HW_;   // 4 x 36864 floats
    float* wt2  = wt1 + C_ * C_ * K_;
    float* wt3  = wt2 + C_ * C_ * K_;
    float* wtd  = wt3 + C_ * C_ * K_;

    dim3 cgrid(W_ / TX, H_ / TY, B_);             // 4 x 16 x 8 = 512 blocks

    wtrans_kernel<<<144, 256, 0, stream>>>(w1, wt1);
    wtrans_kernel<<<144, 256, 0, stream>>>(w2, wt2);
    wtrans_kernel<<<144, 256, 0, stream>>>(w3, wt3);
    wtrans_kernel<<<144, 256, 0, stream>>>(w_d, wtd);
    offconv_kernel<<<512, 256, 0, stream>>>(of, w_off, b_off, offb);

    conv3x3_relu_kernel<<<cgrid, 256, 0, stream>>>(x,   wt1, b1, h1);
    conv3x3_relu_kernel<<<cgrid, 256, 0, stream>>>(h1,  wt2, b2, out);  // d_out as scratch
    conv3x3_relu_kernel<<<cgrid, 256, 0, stream>>>(out, wt3, b3, h1);
    deform_kernel<<<512, 256, 0, stream>>>(h1, offb, wtd, b_d, out);
}

// Round 2
// 202.532 us; speedup vs baseline: 4.4565x; 4.4565x over previous
//
#include <hip/hip_runtime.h>
#include <math.h>

#define H_ 128
#define W_ 128
#define B_ 8
#define C_ 64
#define HW_ (H_*W_)
#define PW 130            // padded width/height (halo 1)

typedef _Float16 half8 __attribute__((ext_vector_type(8)));
typedef _Float16 half4t __attribute__((ext_vector_type(4)));
typedef float f32x4 __attribute__((ext_vector_type(4)));

__device__ __forceinline__ int clampi(int v, int lo, int hi) {
    return v < lo ? lo : (v > hi ? hi : v);
}

// ---- weight prepack into A-fragment order ----
// wp[((kk*2+ch)*4+mf)*64 + l][j] = w[co][cin][kk], co=16*mf+(l&15), cin=32*ch+8*(l>>4)+j
__global__ void wpack_kernel(const float* __restrict__ w, _Float16* __restrict__ wp) {
    int t = blockIdx.x * 256 + threadIdx.x;
    if (t >= 9 * 2 * 4 * 64) return;
    int l  = t & 63;
    int mf = (t >> 6) & 3;
    int ch = (t >> 8) & 1;
    int kk = t >> 9;
    int co   = mf * 16 + (l & 15);
    int cin0 = ch * 32 + (l >> 4) * 8;
    half8 v;
#pragma unroll
    for (int j = 0; j < 8; ++j)
        v[j] = (_Float16)w[((co * C_) + cin0 + j) * 9 + kk];
    *(half8*)(wp + (size_t)t * 8) = v;
}

// ---- fp32 NCHW -> padded NHWC f16 (zeros in halo) ----
__global__ void xpad_kernel(const float* __restrict__ x, _Float16* __restrict__ o) {
    int t = blockIdx.x * 256 + threadIdx.x;  // over B*130*130
    if (t >= B_ * PW * PW) return;
    int b  = t / (PW * PW);
    int r  = t % (PW * PW);
    int yp = r / PW, xp = r % PW;
    _Float16* dst = o + (size_t)t * C_;
    if (yp == 0 || yp == PW - 1 || xp == 0 || xp == PW - 1) {
        half8 z = (half8)(_Float16)0.f;
#pragma unroll
        for (int c8 = 0; c8 < 8; ++c8) *(half8*)(dst + c8 * 8) = z;
        return;
    }
    const float* src = x + (size_t)b * C_ * HW_ + (yp - 1) * W_ + (xp - 1);
#pragma unroll
    for (int c8 = 0; c8 < 8; ++c8) {
        half8 v;
#pragma unroll
        for (int i = 0; i < 8; ++i) v[i] = (_Float16)src[(c8 * 8 + i) * HW_];
        *(half8*)(dst + c8 * 8) = v;
    }
}

// ---- zero the halo cells of a padded NHWC array ----
__global__ void zpad_kernel(_Float16* __restrict__ o) {
    int t = blockIdx.x * 256 + threadIdx.x;  // over B * 516 border px
    if (t >= B_ * 516) return;
    int b = t / 516, i = t % 516;
    int yp, xp;
    if (i < 260) { yp = (i < 130) ? 0 : (PW - 1); xp = i % 130; }
    else {
        int j = i - 260;
        if (j < 128) { xp = 0; yp = j + 1; }
        else         { xp = PW - 1; yp = j - 128 + 1; }
    }
    _Float16* dst = o + ((size_t)(b * PW + yp) * PW + xp) * C_;
    half8 z = (half8)(_Float16)0.f;
#pragma unroll
    for (int c8 = 0; c8 < 8; ++c8) *(half8*)(dst + c8 * 8) = z;
}

// ---- 1x1 offset conv: of[B,2,H,W] -> off[B,18,H,W] fp32 ----
__global__ void offconv_kernel(const float* __restrict__ of,
                               const float* __restrict__ w,   // [18][2]
                               const float* __restrict__ b,
                               float* __restrict__ out) {
    int t = blockIdx.x * 256 + threadIdx.x;
    if (t >= B_ * HW_) return;
    int bi = t >> 14;
    int p  = t & (HW_ - 1);
    float a0 = of[(bi * 2 + 0) * HW_ + p];
    float a1 = of[(bi * 2 + 1) * HW_ + p];
#pragma unroll
    for (int c = 0; c < 18; ++c)
        out[(bi * 18 + c) * HW_ + p] = b[c] + w[c * 2] * a0 + w[c * 2 + 1] * a1;
}

// ---- 3x3 conv + bias + relu via MFMA; padded NHWC f16 in/out ----
__global__ __launch_bounds__(256, 2)
void conv3x3_mfma(const _Float16* __restrict__ in, const _Float16* __restrict__ wpk,
                  const float* __restrict__ bias, _Float16* __restrict__ outp) {
    const int tid = threadIdx.x;
    const int wv = tid >> 6, l = tid & 63;
    const int l15 = l & 15, lg = l >> 4;
    const int b  = blockIdx.y;
    const int ry = blockIdx.x * 2 + (wv >> 1);
    const int xh = (wv & 1) * 64;

    f32x4 acc[4][4];
#pragma unroll
    for (int i = 0; i < 4; ++i)
#pragma unroll
        for (int j = 0; j < 4; ++j) acc[i][j] = (f32x4){0.f, 0.f, 0.f, 0.f};

    const int laneB = l15 * C_ + lg * 8;

#pragma unroll
    for (int kk = 0; kk < 9; ++kk) {
        const int dy = kk / 3, dx = kk % 3;
        const _Float16* rowb = in + ((size_t)((b * PW + ry + dy) * PW + xh + dx)) * C_;
#pragma unroll
        for (int ch = 0; ch < 2; ++ch) {
            half8 af[4];
#pragma unroll
            for (int mf = 0; mf < 4; ++mf)
                af[mf] = *(const half8*)(wpk + ((size_t)(((kk * 2 + ch) * 4 + mf) * 64 + l)) * 8);
            half8 bf[4];
#pragma unroll
            for (int nf = 0; nf < 4; ++nf)
                bf[nf] = *(const half8*)(rowb + nf * 16 * C_ + laneB + ch * 32);
#pragma unroll
            for (int mf = 0; mf < 4; ++mf)
#pragma unroll
                for (int nf = 0; nf < 4; ++nf)
                    acc[mf][nf] = __builtin_amdgcn_mfma_f32_16x16x32_f16(af[mf], bf[nf], acc[mf][nf], 0, 0, 0);
        }
    }

    _Float16* ob = outp + ((size_t)((b * PW + ry + 1) * PW + xh + 1)) * C_;
#pragma unroll
    for (int mf = 0; mf < 4; ++mf) {
        const int co = mf * 16 + lg * 4;
        const float b0 = bias[co], b1 = bias[co + 1], b2 = bias[co + 2], b3 = bias[co + 3];
#pragma unroll
        for (int nf = 0; nf < 4; ++nf) {
            f32x4 v = acc[mf][nf];
            half4t h;
            h[0] = (_Float16)fmaxf(v[0] + b0, 0.f);
            h[1] = (_Float16)fmaxf(v[1] + b1, 0.f);
            h[2] = (_Float16)fmaxf(v[2] + b2, 0.f);
            h[3] = (_Float16)fmaxf(v[3] + b3, 0.f);
            *(half4t*)(ob + (nf * 16 + l15) * C_ + co) = h;
        }
    }
}

// ---- deformable conv via bilinear gather + MFMA ----
__global__ __launch_bounds__(256, 2)
void deform_mfma(const _Float16* __restrict__ hin, const float* __restrict__ off,
                 const _Float16* __restrict__ wpk, const float* __restrict__ bias,
                 float* __restrict__ out) {
    const int tid = threadIdx.x;
    const int wv = tid >> 6, l = tid & 63;
    const int l15 = l & 15, lg = l >> 4;
    const int b  = blockIdx.y;
    const int ry = blockIdx.x * 2 + (wv >> 1);
    const int xh = (wv & 1) * 64;

    f32x4 acc[4][4];
#pragma unroll
    for (int i = 0; i < 4; ++i)
#pragma unroll
        for (int j = 0; j < 4; ++j) acc[i][j] = (f32x4){0.f, 0.f, 0.f, 0.f};

    const float* offb = off + (size_t)b * 18 * HW_;
    const _Float16* hb = hin + (size_t)b * PW * PW * C_;

    for (int kk = 0; kk < 9; ++kk) {
        const int dy = kk / 3, dx = kk % 3;
        half8 bf[2][4];
#pragma unroll
        for (int nf = 0; nf < 4; ++nf) {
            const int x = xh + nf * 16 + l15;
            const int p = ry * W_ + x;
            float oy = offb[(2 * kk) * HW_ + p];
            float ox = offb[(2 * kk + 1) * HW_ + p];
            float py = (float)(ry + dy - 1) + oy;
            float px = (float)(x + dx - 1) + ox;
            float fy0 = floorf(py), fx0 = floorf(px);
            float fy = py - fy0, fx = px - fx0;
            int iy0 = (int)fy0, ix0 = (int)fx0;
            int cy0 = clampi(iy0, -1, 128), cy1 = clampi(iy0 + 1, -1, 128);
            int cx0 = clampi(ix0, -1, 128), cx1 = clampi(ix0 + 1, -1, 128);
            _Float16 w00 = (_Float16)((1.f - fy) * (1.f - fx));
            _Float16 w01 = (_Float16)((1.f - fy) * fx);
            _Float16 w10 = (_Float16)(fy * (1.f - fx));
            _Float16 w11 = (_Float16)(fy * fx);
            const _Float16* r0 = hb + ((size_t)((cy0 + 1) * PW + 1)) * C_;
            const _Float16* r1 = hb + ((size_t)((cy1 + 1) * PW + 1)) * C_;
#pragma unroll
            for (int ch = 0; ch < 2; ++ch) {
                const int o = ch * 32 + lg * 8;
                half8 c00 = *(const half8*)(r0 + cx0 * C_ + o);
                half8 c01 = *(const half8*)(r0 + cx1 * C_ + o);
                half8 c10 = *(const half8*)(r1 + cx0 * C_ + o);
                half8 c11 = *(const half8*)(r1 + cx1 * C_ + o);
                bf[ch][nf] = c00 * w00 + c01 * w01 + c10 * w10 + c11 * w11;
            }
        }
#pragma unroll
        for (int ch = 0; ch < 2; ++ch) {
            half8 af[4];
#pragma unroll
            for (int mf = 0; mf < 4; ++mf)
                af[mf] = *(const half8*)(wpk + ((size_t)(((kk * 2 + ch) * 4 + mf) * 64 + l)) * 8);
#pragma unroll
            for (int mf = 0; mf < 4; ++mf)
#pragma unroll
                for (int nf = 0; nf < 4; ++nf)
                    acc[mf][nf] = __builtin_amdgcn_mfma_f32_16x16x32_f16(af[mf], bf[ch][nf], acc[mf][nf], 0, 0, 0);
        }
    }

    float* ob = out + (size_t)b * C_ * HW_ + ry * W_ + xh;
#pragma unroll
    for (int mf = 0; mf < 4; ++mf) {
        const int co = mf * 16 + lg * 4;
#pragma unroll
        for (int nf = 0; nf < 4; ++nf) {
            f32x4 v = acc[mf][nf];
#pragma unroll
            for (int r = 0; r < 4; ++r)
                ob[(size_t)(co + r) * HW_ + nf * 16 + l15] = v[r] + bias[co + r];
        }
    }
}

extern "C" void kernel_launch(void* const* d_in, const int* in_sizes, int n_in,
                              void* d_out, int out_size, void* d_ws, size_t ws_size,
                              hipStream_t stream) {
    const float* x     = (const float*)d_in[0];
    const float* of    = (const float*)d_in[1];
    const float* w1    = (const float*)d_in[2];
    const float* b1    = (const float*)d_in[3];
    const float* w2    = (const float*)d_in[4];
    const float* b2    = (const float*)d_in[5];
    const float* w3    = (const float*)d_in[6];
    const float* b3    = (const float*)d_in[7];
    const float* w_off = (const float*)d_in[8];
    const float* b_off = (const float*)d_in[9];
    const float* w_d   = (const float*)d_in[10];
    const float* b_d   = (const float*)d_in[11];
    float* out = (float*)d_out;

    char* base = (char*)d_ws;
    float*     offb = (float*)base;                           // 8*18*16384 f32 = 9.44 MB
    char* p = base + (size_t)B_ * 18 * HW_ * 4;
    _Float16* wp1 = (_Float16*)p; p += 9 * 2 * 4 * 64 * 8 * 2;  // 73728 B each
    _Float16* wp2 = (_Float16*)p; p += 9 * 2 * 4 * 64 * 8 * 2;
    _Float16* wp3 = (_Float16*)p; p += 9 * 2 * 4 * 64 * 8 * 2;
    _Float16* wpd = (_Float16*)p; p += 9 * 2 * 4 * 64 * 8 * 2;
    _Float16* xp = (_Float16*)p; p += (size_t)B_ * PW * PW * C_ * 2;  // 17.3 MB
    _Float16* hA = (_Float16*)p; p += (size_t)B_ * PW * PW * C_ * 2;
    _Float16* hB = (_Float16*)p;

    wpack_kernel<<<18, 256, 0, stream>>>(w1, wp1);
    wpack_kernel<<<18, 256, 0, stream>>>(w2, wp2);
    wpack_kernel<<<18, 256, 0, stream>>>(w3, wp3);
    wpack_kernel<<<18, 256, 0, stream>>>(w_d, wpd);
    xpad_kernel<<<(B_ * PW * PW + 255) / 256, 256, 0, stream>>>(x, xp);
    zpad_kernel<<<(B_ * 516 + 255) / 256, 256, 0, stream>>>(hA);
    zpad_kernel<<<(B_ * 516 + 255) / 256, 256, 0, stream>>>(hB);
    offconv_kernel<<<(B_ * HW_ + 255) / 256, 256, 0, stream>>>(of, w_off, b_off, offb);

    dim3 grid(H_ / 2, B_);
    conv3x3_mfma<<<grid, 256, 0, stream>>>(xp, wp1, b1, hA);
    conv3x3_mfma<<<grid, 256, 0, stream>>>(hA, wp2, b2, hB);
    conv3x3_mfma<<<grid, 256, 0, stream>>>(hB, wp3, b3, hA);
    deform_mfma<<<grid, 256, 0, stream>>>(hA, offb, wpd, b_d, out);
}